// Round 9
// baseline (113.816 us; speedup 1.0000x reference)
//
#include <hip/hip_runtime.h>

// PGNN: N=50000 nodes, K=32 anchors/edges per node, E=1.6M edges
// out: normalize(out_position)[N,32] f32
constexpr int NN = 50000;
constexpr int KANCH = 32;

typedef __attribute__((ext_vector_type(8))) short bfrag;   // 8 bf16 (4 VGPR)
typedef __attribute__((ext_vector_type(4))) float ffrag;   // 4 f32 acc

static __device__ __forceinline__ float bf2f(unsigned short u) {
    return __uint_as_float(((unsigned int)u) << 16);
}
static __device__ __forceinline__ unsigned short f2bf(float f) {
    unsigned int x = __float_as_uint(f);
    x += 0x7FFFu + ((x >> 16) & 1u);   // round-to-nearest-even
    return (unsigned short)(x >> 16);
}

// ---------------------------------------------------------------------------
// K0: compose layer-1 weights through the pre-linear; pack weights to bf16.
// wcat1[j][i] = bf16((Wu1|Wv1)@w_pre) [128][128]; bias1 = (Wu1|Wv1)@b_pre+b
// wcat2[j][i] = bf16(Wu2|Wv2) [64][64]
// ---------------------------------------------------------------------------
__global__ __launch_bounds__(256) void k_prep(
    const float* __restrict__ w_pre, const float* __restrict__ b_pre,
    const float* __restrict__ Wu1, const float* __restrict__ bu1,
    const float* __restrict__ Wv1, const float* __restrict__ bv1,
    const float* __restrict__ Wu2, const float* __restrict__ Wv2,
    unsigned short* __restrict__ wcat1, float* __restrict__ bias1,
    unsigned short* __restrict__ wcat2)
{
    int gid = blockIdx.x * 256 + threadIdx.x;
    if (gid < 16384) {
        int j = gid >> 7, i = gid & 127;
        const float* Wr = (j < 64) ? (Wu1 + j * 64) : (Wv1 + (j - 64) * 64);
        float a = 0.f;
        for (int t = 0; t < 64; ++t) a += Wr[t] * w_pre[t * 128 + i];
        wcat1[gid] = f2bf(a);
    } else if (gid < 16384 + 4096) {
        int g = gid - 16384;
        int j = g >> 6, i = g & 63;
        float w = (j < 32) ? Wu2[j * 64 + i] : Wv2[(j - 32) * 64 + i];
        wcat2[g] = f2bf(w);
    } else if (gid < 16384 + 4096 + 128) {
        int j = gid - (16384 + 4096);
        const float* Wr = (j < 64) ? (Wu1 + j * 64) : (Wv1 + (j - 64) * 64);
        float a = (j < 64) ? bu1[j] : bv1[j - 64];
        for (int t = 0; t < 64; ++t) a += Wr[t] * b_pre[t];
        bias1[j] = a;
    }
}

// ---------------------------------------------------------------------------
// K1: layer-1 u/v linears via MFMA.  [NN][64] bf16 tables (round-5 verified).
// A (feat f32) split in-register into bf16 hi+lo (exact; 2 MFMAs per step).
// ---------------------------------------------------------------------------
__global__ __launch_bounds__(256) void k_gemm1(
    const float* __restrict__ feat,            // [NN][128]
    const unsigned short* __restrict__ wcat,   // [128][128] bf16
    const float* __restrict__ bias,            // [128] f32
    unsigned short* __restrict__ ub,           // [NN][64] bf16
    unsigned short* __restrict__ vb,           // [NN][64] bf16
    int nTiles)                                // NN/16
{
    __shared__ unsigned short s_w[128 * 136];  // 272 B row stride
    __shared__ float s_b[128];
    int tid = threadIdx.x;
    for (int idx = tid; idx < 128 * 16; idx += 256) {
        int r = idx >> 4, c8 = idx & 15;
        const uint4* g = reinterpret_cast<const uint4*>(wcat + r * 128 + c8 * 8);
        *reinterpret_cast<uint4*>(&s_w[r * 136 + c8 * 8]) = *g;
    }
    if (tid < 128) s_b[tid] = bias[tid];
    __syncthreads();

    int wv = __builtin_amdgcn_readfirstlane(tid >> 6);
    int lane = tid & 63;
    int col = lane & 15;        // A row (node) / D col (out) / W row
    int grp = lane >> 4;        // k-subchunk 0..3
    int slot = blockIdx.x * 4 + wv;
    int stride = gridDim.x * 4;
    for (int tile = slot; tile < nTiles; tile += stride) {
        int n0 = tile * 16;
        const float* fp = feat + (size_t)(n0 + col) * 128 + grp * 8;
        bfrag AH[4], AL[4];
#pragma unroll
        for (int s = 0; s < 4; ++s) {
            float4 p0 = *reinterpret_cast<const float4*>(fp + s * 32);
            float4 p1 = *reinterpret_cast<const float4*>(fp + s * 32 + 4);
            float a8[8] = {p0.x, p0.y, p0.z, p0.w, p1.x, p1.y, p1.z, p1.w};
#pragma unroll
            for (int e = 0; e < 8; ++e) {
                unsigned short hb = f2bf(a8[e]);
                AH[s][e] = (short)hb;
                AL[s][e] = (short)f2bf(a8[e] - bf2f(hb));
            }
        }
#pragma unroll
        for (int t = 0; t < 8; ++t) {
            ffrag a = {0.f, 0.f, 0.f, 0.f};
#pragma unroll
            for (int s = 0; s < 4; ++s) {
                const bfrag w = *reinterpret_cast<const bfrag*>(
                    &s_w[(t * 16 + col) * 136 + s * 32 + grp * 8]);
                a = __builtin_amdgcn_mfma_f32_16x16x32_bf16(AH[s], w, a, 0, 0, 0);
                a = __builtin_amdgcn_mfma_f32_16x16x32_bf16(AL[s], w, a, 0, 0, 0);
            }
            float bb = s_b[t * 16 + col];
#pragma unroll
            for (int j = 0; j < 4; ++j) {
                int node = n0 + grp * 4 + j;
                unsigned short o = f2bf(a[j] + bb);
                if (t < 4) ub[(size_t)node * 64 + t * 16 + col] = o;
                else       vb[(size_t)node * 64 + (t - 4) * 16 + col] = o;
            }
        }
    }
}

// ---------------------------------------------------------------------------
// K2: FUSED layer-1 aggregation + layer-2 linears via MFMA.
// Wave batch = 16 nodes, gathered as 8 PAIR-iterations with the round-5
// A/B structure (32 table loads in flight per iteration -> full MLP).
// x2 rows -> bf16x4 into wave-private LDS tile [16][72] (144 B stride).
// Then ONE full 16-row MFMA phase (2 ds_read_b128 + 8 MFMA, all rows real)
// + round-5 gemm2 epilogue. No x2 global round-trip, no gemm2 dispatch.
// ---------------------------------------------------------------------------
__global__ __launch_bounds__(256) void k_fuse2(
    const ushort4* __restrict__ u1v, const ushort4* __restrict__ v1v, // [NN*16]
    const int* __restrict__ src, const int* __restrict__ dst,
    const float* __restrict__ dists,
    const unsigned short* __restrict__ wcat2,  // [64][64] bf16
    const float* __restrict__ bu2, const float* __restrict__ bv2,
    unsigned short* __restrict__ u2b,          // [NN][32] bf16
    unsigned short* __restrict__ v2b)          // [NN][32] bf16
{
    __shared__ unsigned short s_x2[4][16 * 72];   // per-wave [16 nodes][72] tile
    int tid = threadIdx.x;
    int wv = __builtin_amdgcn_readfirstlane(tid >> 6);
    int lane = tid & 63;
    int c = lane & 15;      // gather: dim chunk / MFMA: out-col & A-row
    int es = lane >> 4;     // gather: edge subgroup / MFMA: k-group & row-group
    // ---- one-time: preload B-fragments of W2cat and bias ----
    bfrag Bf[4][2];
#pragma unroll
    for (int t = 0; t < 4; ++t)
#pragma unroll
        for (int s = 0; s < 2; ++s) {
            uint4 raw = *reinterpret_cast<const uint4*>(
                wcat2 + (t * 16 + c) * 64 + s * 32 + es * 8);
            Bf[t][s] = *reinterpret_cast<const bfrag*>(&raw);
        }
    float bb[4];
#pragma unroll
    for (int t = 0; t < 4; ++t)
        bb[t] = (t < 2) ? bu2[t * 16 + c] : bv2[(t - 2) * 16 + c];

    unsigned short* sx = &s_x2[wv][0];
    int slot = blockIdx.x * 4 + wv;
    int stride = gridDim.x * 4;
    const int nBatch = NN / 16;           // 3125
    for (int b = slot; b < nBatch; b += stride) {
        int n0 = b * 16;
        // ---- gather phase: 8 pair-iterations (round-5 A/B body) ----
        for (int ii = 0; ii < 8; ++ii) {
            int nA = n0 + ii * 2, nB = nA + 1;
            int baseA = nA * KANCH, baseB = nB * KANCH;
            int4   sA0 = *reinterpret_cast<const int4*>(src + baseA + es * 8);
            int4   sA1 = *reinterpret_cast<const int4*>(src + baseA + es * 8 + 4);
            int4   dA0 = *reinterpret_cast<const int4*>(dst + baseA + es * 8);
            int4   dA1 = *reinterpret_cast<const int4*>(dst + baseA + es * 8 + 4);
            float4 pA0 = *reinterpret_cast<const float4*>(dists + baseA + es * 8);
            float4 pA1 = *reinterpret_cast<const float4*>(dists + baseA + es * 8 + 4);
            int4   sB0 = *reinterpret_cast<const int4*>(src + baseB + es * 8);
            int4   sB1 = *reinterpret_cast<const int4*>(src + baseB + es * 8 + 4);
            int4   dB0 = *reinterpret_cast<const int4*>(dst + baseB + es * 8);
            int4   dB1 = *reinterpret_cast<const int4*>(dst + baseB + es * 8 + 4);
            float4 pB0 = *reinterpret_cast<const float4*>(dists + baseB + es * 8);
            float4 pB1 = *reinterpret_cast<const float4*>(dists + baseB + es * 8 + 4);
            ushort4 uA[8], vA[8], uB[8], vB[8];
            uA[0] = u1v[(size_t)sA0.x * 16 + c]; uA[1] = u1v[(size_t)sA0.y * 16 + c];
            uA[2] = u1v[(size_t)sA0.z * 16 + c]; uA[3] = u1v[(size_t)sA0.w * 16 + c];
            uA[4] = u1v[(size_t)sA1.x * 16 + c]; uA[5] = u1v[(size_t)sA1.y * 16 + c];
            uA[6] = u1v[(size_t)sA1.z * 16 + c]; uA[7] = u1v[(size_t)sA1.w * 16 + c];
            vA[0] = v1v[(size_t)dA0.x * 16 + c]; vA[1] = v1v[(size_t)dA0.y * 16 + c];
            vA[2] = v1v[(size_t)dA0.z * 16 + c]; vA[3] = v1v[(size_t)dA0.w * 16 + c];
            vA[4] = v1v[(size_t)dA1.x * 16 + c]; vA[5] = v1v[(size_t)dA1.y * 16 + c];
            vA[6] = v1v[(size_t)dA1.z * 16 + c]; vA[7] = v1v[(size_t)dA1.w * 16 + c];
            uB[0] = u1v[(size_t)sB0.x * 16 + c]; uB[1] = u1v[(size_t)sB0.y * 16 + c];
            uB[2] = u1v[(size_t)sB0.z * 16 + c]; uB[3] = u1v[(size_t)sB0.w * 16 + c];
            uB[4] = u1v[(size_t)sB1.x * 16 + c]; uB[5] = u1v[(size_t)sB1.y * 16 + c];
            uB[6] = u1v[(size_t)sB1.z * 16 + c]; uB[7] = u1v[(size_t)sB1.w * 16 + c];
            vB[0] = v1v[(size_t)dB0.x * 16 + c]; vB[1] = v1v[(size_t)dB0.y * 16 + c];
            vB[2] = v1v[(size_t)dB0.z * 16 + c]; vB[3] = v1v[(size_t)dB0.w * 16 + c];
            vB[4] = v1v[(size_t)dB1.x * 16 + c]; vB[5] = v1v[(size_t)dB1.y * 16 + c];
            vB[6] = v1v[(size_t)dB1.z * 16 + c]; vB[7] = v1v[(size_t)dB1.w * 16 + c];

            float spA[8] = {pA0.x, pA0.y, pA0.z, pA0.w, pA1.x, pA1.y, pA1.z, pA1.w};
            float spB[8] = {pB0.x, pB0.y, pB0.z, pB0.w, pB1.x, pB1.y, pB1.z, pB1.w};
            float a0 = 0.f, a1 = 0.f, a2 = 0.f, a3 = 0.f;
            float b0 = 0.f, b1 = 0.f, b2 = 0.f, b3 = 0.f;
#pragma unroll
            for (int kk = 0; kk < 8; ++kk) {
                a0 += fmaxf(fmaf(bf2f(uA[kk].x), spA[kk], bf2f(vA[kk].x)), 0.f);
                a1 += fmaxf(fmaf(bf2f(uA[kk].y), spA[kk], bf2f(vA[kk].y)), 0.f);
                a2 += fmaxf(fmaf(bf2f(uA[kk].z), spA[kk], bf2f(vA[kk].z)), 0.f);
                a3 += fmaxf(fmaf(bf2f(uA[kk].w), spA[kk], bf2f(vA[kk].w)), 0.f);
                b0 += fmaxf(fmaf(bf2f(uB[kk].x), spB[kk], bf2f(vB[kk].x)), 0.f);
                b1 += fmaxf(fmaf(bf2f(uB[kk].y), spB[kk], bf2f(vB[kk].y)), 0.f);
                b2 += fmaxf(fmaf(bf2f(uB[kk].z), spB[kk], bf2f(vB[kk].z)), 0.f);
                b3 += fmaxf(fmaf(bf2f(uB[kk].w), spB[kk], bf2f(vB[kk].w)), 0.f);
            }
            a0 += __shfl_xor(a0, 16); a0 += __shfl_xor(a0, 32);
            a1 += __shfl_xor(a1, 16); a1 += __shfl_xor(a1, 32);
            a2 += __shfl_xor(a2, 16); a2 += __shfl_xor(a2, 32);
            a3 += __shfl_xor(a3, 16); a3 += __shfl_xor(a3, 32);
            b0 += __shfl_xor(b0, 16); b0 += __shfl_xor(b0, 32);
            b1 += __shfl_xor(b1, 16); b1 += __shfl_xor(b1, 32);
            b2 += __shfl_xor(b2, 16); b2 += __shfl_xor(b2, 32);
            b3 += __shfl_xor(b3, 16); b3 += __shfl_xor(b3, 32);
            if (lane < 16) {
                ushort4 r;
                r.x = f2bf(a0 * 0.03125f); r.y = f2bf(a1 * 0.03125f);
                r.z = f2bf(a2 * 0.03125f); r.w = f2bf(a3 * 0.03125f);
                *reinterpret_cast<ushort4*>(&sx[(ii * 2) * 72 + c * 4]) = r;
            } else if (lane < 32) {
                ushort4 r;
                r.x = f2bf(b0 * 0.03125f); r.y = f2bf(b1 * 0.03125f);
                r.z = f2bf(b2 * 0.03125f); r.w = f2bf(b3 * 0.03125f);
                *reinterpret_cast<ushort4*>(&sx[(ii * 2 + 1) * 72 + c * 4]) = r;
            }
        }
        // ---- MFMA phase: full 16-row x2 tile @ W2cat^T -> u2/v2 rows ----
        bfrag A[2];
#pragma unroll
        for (int s = 0; s < 2; ++s)
            A[s] = *reinterpret_cast<const bfrag*>(
                &sx[c * 72 + s * 32 + es * 8]);
        ffrag acc[4];
#pragma unroll
        for (int t = 0; t < 4; ++t) {
            acc[t] = ffrag{0.f, 0.f, 0.f, 0.f};
#pragma unroll
            for (int s = 0; s < 2; ++s)
                acc[t] = __builtin_amdgcn_mfma_f32_16x16x32_bf16(
                    A[s], Bf[t][s], acc[t], 0, 0, 0);
        }
#pragma unroll
        for (int t = 0; t < 4; ++t) {
#pragma unroll
            for (int j = 0; j < 4; ++j) {
                int node = n0 + es * 4 + j;
                unsigned short o = f2bf(acc[t][j] + bb[t]);
                if (t < 2) u2b[(size_t)node * 32 + t * 16 + c] = o;
                else       v2b[(size_t)node * 32 + (t - 2) * 16 + c] = o;
            }
        }
    }
}

// ---------------------------------------------------------------------------
// K3: layer-2 message + position dot + L2 normalize (round-5 verified).
// Wave handles TWO nodes per iter; lane = (es=lane>>3, c=lane&7).
// ---------------------------------------------------------------------------
__global__ __launch_bounds__(256, 4) void k_out(
    const ushort4* __restrict__ u2v, const ushort4* __restrict__ v2v, // [NN*8]
    const int* __restrict__ src, const int* __restrict__ dst,
    const float* __restrict__ dists, const float* __restrict__ wp2,
    const float* __restrict__ bp2, float* __restrict__ out)
{
    int tid = threadIdx.x;
    int wv = __builtin_amdgcn_readfirstlane(tid >> 6);
    int lane = tid & 63;
    int c = lane & 7;       // dims 4c..4c+3
    int es = lane >> 3;     // edge subgroup 0..7 (k = es*4 + kk)
    int slot = blockIdx.x * 4 + wv;
    int stride = gridDim.x * 4;
    float4 w4 = reinterpret_cast<const float4*>(wp2)[c];
    float bp = bp2[0];
    const int nPairs = NN / 2;
    for (int p = slot; p < nPairs; p += stride) {
        int nA = p * 2, nB = nA + 1;
        int baseA = nA * KANCH, baseB = nB * KANCH;
        int4   sA = *reinterpret_cast<const int4*>(src + baseA + es * 4);
        int4   dA = *reinterpret_cast<const int4*>(dst + baseA + es * 4);
        float4 pA = *reinterpret_cast<const float4*>(dists + baseA + es * 4);
        int4   sB = *reinterpret_cast<const int4*>(src + baseB + es * 4);
        int4   dB = *reinterpret_cast<const int4*>(dst + baseB + es * 4);
        float4 pB = *reinterpret_cast<const float4*>(dists + baseB + es * 4);
        ushort4 uA[4], vA[4], uB[4], vB[4];
        uA[0] = u2v[(size_t)sA.x * 8 + c]; uA[1] = u2v[(size_t)sA.y * 8 + c];
        uA[2] = u2v[(size_t)sA.z * 8 + c]; uA[3] = u2v[(size_t)sA.w * 8 + c];
        vA[0] = v2v[(size_t)dA.x * 8 + c]; vA[1] = v2v[(size_t)dA.y * 8 + c];
        vA[2] = v2v[(size_t)dA.z * 8 + c]; vA[3] = v2v[(size_t)dA.w * 8 + c];
        uB[0] = u2v[(size_t)sB.x * 8 + c]; uB[1] = u2v[(size_t)sB.y * 8 + c];
        uB[2] = u2v[(size_t)sB.z * 8 + c]; uB[3] = u2v[(size_t)sB.w * 8 + c];
        vB[0] = v2v[(size_t)dB.x * 8 + c]; vB[1] = v2v[(size_t)dB.y * 8 + c];
        vB[2] = v2v[(size_t)dB.z * 8 + c]; vB[3] = v2v[(size_t)dB.w * 8 + c];
        float spA[4] = {pA.x, pA.y, pA.z, pA.w};
        float spB[4] = {pB.x, pB.y, pB.z, pB.w};
        float qA[4], qB[4];
#pragma unroll
        for (int kk = 0; kk < 4; ++kk) {
            float pa, pb;
            pa  = fmaxf(fmaf(bf2f(uA[kk].x), spA[kk], bf2f(vA[kk].x)), 0.f) * w4.x;
            pa += fmaxf(fmaf(bf2f(uA[kk].y), spA[kk], bf2f(vA[kk].y)), 0.f) * w4.y;
            pa += fmaxf(fmaf(bf2f(uA[kk].z), spA[kk], bf2f(vA[kk].z)), 0.f) * w4.z;
            pa += fmaxf(fmaf(bf2f(uA[kk].w), spA[kk], bf2f(vA[kk].w)), 0.f) * w4.w;
            pb  = fmaxf(fmaf(bf2f(uB[kk].x), spB[kk], bf2f(vB[kk].x)), 0.f) * w4.x;
            pb += fmaxf(fmaf(bf2f(uB[kk].y), spB[kk], bf2f(vB[kk].y)), 0.f) * w4.y;
            pb += fmaxf(fmaf(bf2f(uB[kk].z), spB[kk], bf2f(vB[kk].z)), 0.f) * w4.z;
            pb += fmaxf(fmaf(bf2f(uB[kk].w), spB[kk], bf2f(vB[kk].w)), 0.f) * w4.w;
            pa += __shfl_xor(pa, 1); pa += __shfl_xor(pa, 2); pa += __shfl_xor(pa, 4);
            pb += __shfl_xor(pb, 1); pb += __shfl_xor(pb, 2); pb += __shfl_xor(pb, 4);
            qA[kk] = pa; qB[kk] = pb;
        }
        int t = lane & 31;
        int srcl = (t >> 2) * 8;
        float cA0 = __shfl(qA[0], srcl), cA1 = __shfl(qA[1], srcl);
        float cA2 = __shfl(qA[2], srcl), cA3 = __shfl(qA[3], srcl);
        float cB0 = __shfl(qB[0], srcl), cB1 = __shfl(qB[1], srcl);
        float cB2 = __shfl(qB[2], srcl), cB3 = __shfl(qB[3], srcl);
        int ks = t & 3;
        float qa = (ks == 0) ? cA0 : (ks == 1) ? cA1 : (ks == 2) ? cA2 : cA3;
        float qb = (ks == 0) ? cB0 : (ks == 1) ? cB1 : (ks == 2) ? cB2 : cB3;
        float q = ((lane < 32) ? qa : qb) + bp;
        float ss = q * q;
#pragma unroll
        for (int off = 16; off >= 1; off >>= 1)
            ss += __shfl_xor(ss, off);     // stays within each 32-lane half
        float den = fmaxf(sqrtf(ss), 1e-12f);
        float o = q / den;
        if (lane < 32) out[(size_t)nA * KANCH + t] = o;
        else           out[(size_t)nB * KANCH + t] = o;
    }
}

// ---------------------------------------------------------------------------
extern "C" void kernel_launch(void* const* d_in, const int* in_sizes, int n_in,
                              void* d_out, int out_size, void* d_ws, size_t ws_size,
                              hipStream_t stream)
{
    const float* feat  = (const float*)d_in[0];
    const float* dists = (const float*)d_in[1];
    const int*   src   = (const int*)d_in[2];
    const int*   dst   = (const int*)d_in[3];
    const float* w_pre = (const float*)d_in[4];
    const float* b_pre = (const float*)d_in[5];
    const float* Wu1   = (const float*)d_in[6];
    const float* bu1   = (const float*)d_in[7];
    const float* Wv1   = (const float*)d_in[8];
    const float* bv1   = (const float*)d_in[9];
    // d_in[10]=wp1, d_in[11]=bp1: layer-1 position output is discarded
    const float* Wu2   = (const float*)d_in[12];
    const float* bu2   = (const float*)d_in[13];
    const float* Wv2   = (const float*)d_in[14];
    const float* bv2   = (const float*)d_in[15];
    const float* wp2   = (const float*)d_in[16];
    const float* bp2   = (const float*)d_in[17];
    float* out = (float*)d_out;

    // workspace (~19.2 MB)
    unsigned short* wcat1 = (unsigned short*)d_ws;           // 16384 us
    float* bias1 = (float*)(wcat1 + 16384);                  // 128 f
    unsigned short* wcat2 = (unsigned short*)(bias1 + 128);  // 4096 us
    unsigned short* u1b = wcat2 + 4096;                      // [NN][64]
    unsigned short* v1b = u1b + (size_t)NN * 64;             // [NN][64]
    unsigned short* u2b = v1b + (size_t)NN * 64;             // [NN][32]
    unsigned short* v2b = u2b + (size_t)NN * 32;             // [NN][32]

    k_prep<<<81, 256, 0, stream>>>(w_pre, b_pre, Wu1, bu1, Wv1, bv1,
                                   Wu2, Wv2, wcat1, bias1, wcat2);
    k_gemm1<<<782, 256, 0, stream>>>(feat, wcat1, bias1, u1b, v1b, NN / 16);
    k_fuse2<<<782, 256, 0, stream>>>((const ushort4*)u1b, (const ushort4*)v1b,
                                     src, dst, dists, wcat2, bu2, bv2,
                                     u2b, v2b);
    k_out<<<2048, 256, 0, stream>>>((const ushort4*)u2b, (const ushort4*)v2b,
                                    src, dst, dists, wp2, bp2, out);
}

// Round 10
// 109.709 us; speedup vs baseline: 1.0374x; 1.0374x over previous
//
#include <hip/hip_runtime.h>

// PGNN: N=50000 nodes, K=32 anchors/edges per node, E=1.6M edges
// out: normalize(out_position)[N,32] f32
constexpr int NN = 50000;
constexpr int KANCH = 32;

typedef __attribute__((ext_vector_type(8))) short bfrag;   // 8 bf16 (4 VGPR)
typedef __attribute__((ext_vector_type(4))) float ffrag;   // 4 f32 acc

static __device__ __forceinline__ float bf2f(unsigned short u) {
    return __uint_as_float(((unsigned int)u) << 16);
}
static __device__ __forceinline__ float lo16(unsigned int w) {
    return __uint_as_float(w << 16);
}
static __device__ __forceinline__ float hi16(unsigned int w) {
    return __uint_as_float(w & 0xFFFF0000u);
}
static __device__ __forceinline__ unsigned short f2bf(float f) {
    unsigned int x = __float_as_uint(f);
    x += 0x7FFFu + ((x >> 16) & 1u);   // round-to-nearest-even
    return (unsigned short)(x >> 16);
}
static __device__ __forceinline__ unsigned int pack2(float a, float b) {
    return (unsigned int)f2bf(a) | ((unsigned int)f2bf(b) << 16);
}

// ---------------------------------------------------------------------------
// K0: compose layer-1 weights through the pre-linear; pack weights to bf16.
// ---------------------------------------------------------------------------
__global__ __launch_bounds__(256) void k_prep(
    const float* __restrict__ w_pre, const float* __restrict__ b_pre,
    const float* __restrict__ Wu1, const float* __restrict__ bu1,
    const float* __restrict__ Wv1, const float* __restrict__ bv1,
    const float* __restrict__ Wu2, const float* __restrict__ Wv2,
    unsigned short* __restrict__ wcat1, float* __restrict__ bias1,
    unsigned short* __restrict__ wcat2)
{
    int gid = blockIdx.x * 256 + threadIdx.x;
    if (gid < 16384) {
        int j = gid >> 7, i = gid & 127;
        const float* Wr = (j < 64) ? (Wu1 + j * 64) : (Wv1 + (j - 64) * 64);
        float a = 0.f;
        for (int t = 0; t < 64; ++t) a += Wr[t] * w_pre[t * 128 + i];
        wcat1[gid] = f2bf(a);
    } else if (gid < 16384 + 4096) {
        int g = gid - 16384;
        int j = g >> 6, i = g & 63;
        float w = (j < 32) ? Wu2[j * 64 + i] : Wv2[(j - 32) * 64 + i];
        wcat2[g] = f2bf(w);
    } else if (gid < 16384 + 4096 + 128) {
        int j = gid - (16384 + 4096);
        const float* Wr = (j < 64) ? (Wu1 + j * 64) : (Wv1 + (j - 64) * 64);
        float a = (j < 64) ? bu1[j] : bv1[j - 64];
        for (int t = 0; t < 64; ++t) a += Wr[t] * b_pre[t];
        bias1[j] = a;
    }
}

// ---------------------------------------------------------------------------
// K1: layer-1 u/v linears via MFMA.  [NN][64] bf16 tables (round-5 verified).
// ---------------------------------------------------------------------------
__global__ __launch_bounds__(256) void k_gemm1(
    const float* __restrict__ feat,            // [NN][128]
    const unsigned short* __restrict__ wcat,   // [128][128] bf16
    const float* __restrict__ bias,            // [128] f32
    unsigned short* __restrict__ ub,           // [NN][64] bf16
    unsigned short* __restrict__ vb,           // [NN][64] bf16
    int nTiles)                                // NN/16
{
    __shared__ unsigned short s_w[128 * 136];  // 272 B row stride
    __shared__ float s_b[128];
    int tid = threadIdx.x;
    for (int idx = tid; idx < 128 * 16; idx += 256) {
        int r = idx >> 4, c8 = idx & 15;
        const uint4* g = reinterpret_cast<const uint4*>(wcat + r * 128 + c8 * 8);
        *reinterpret_cast<uint4*>(&s_w[r * 136 + c8 * 8]) = *g;
    }
    if (tid < 128) s_b[tid] = bias[tid];
    __syncthreads();

    int wv = __builtin_amdgcn_readfirstlane(tid >> 6);
    int lane = tid & 63;
    int col = lane & 15;        // A row (node) / D col (out) / W row
    int grp = lane >> 4;        // k-subchunk 0..3
    int slot = blockIdx.x * 4 + wv;
    int stride = gridDim.x * 4;
    for (int tile = slot; tile < nTiles; tile += stride) {
        int n0 = tile * 16;
        const float* fp = feat + (size_t)(n0 + col) * 128 + grp * 8;
        bfrag AH[4], AL[4];
#pragma unroll
        for (int s = 0; s < 4; ++s) {
            float4 p0 = *reinterpret_cast<const float4*>(fp + s * 32);
            float4 p1 = *reinterpret_cast<const float4*>(fp + s * 32 + 4);
            float a8[8] = {p0.x, p0.y, p0.z, p0.w, p1.x, p1.y, p1.z, p1.w};
#pragma unroll
            for (int e = 0; e < 8; ++e) {
                unsigned short hb = f2bf(a8[e]);
                AH[s][e] = (short)hb;
                AL[s][e] = (short)f2bf(a8[e] - bf2f(hb));
            }
        }
#pragma unroll
        for (int t = 0; t < 8; ++t) {
            ffrag a = {0.f, 0.f, 0.f, 0.f};
#pragma unroll
            for (int s = 0; s < 4; ++s) {
                const bfrag w = *reinterpret_cast<const bfrag*>(
                    &s_w[(t * 16 + col) * 136 + s * 32 + grp * 8]);
                a = __builtin_amdgcn_mfma_f32_16x16x32_bf16(AH[s], w, a, 0, 0, 0);
                a = __builtin_amdgcn_mfma_f32_16x16x32_bf16(AL[s], w, a, 0, 0, 0);
            }
            float bb = s_b[t * 16 + col];
#pragma unroll
            for (int j = 0; j < 4; ++j) {
                int node = n0 + grp * 4 + j;
                unsigned short o = f2bf(a[j] + bb);
                if (t < 4) ub[(size_t)node * 64 + t * 16 + col] = o;
                else       vb[(size_t)node * 64 + (t - 4) * 16 + col] = o;
            }
        }
    }
}

// ---------------------------------------------------------------------------
// K2: FUSED layer-1 aggregation + layer-2 linears via MFMA.
// Gather uses 16 B/lane (ushort8/uint4) table loads: lane=(es=lane>>3 edge
// subgroup, c=lane&7 chunk of 8 dims); 8 table loads/node (vs 16 with
// ushort4) -> halves the TA/issue pressure, wave covers 1 KiB per instr.
// es-major indices (k = es*4+kk): one int4/int4/float4 per lane per node.
// Reduce over es = 3 shfl_xor per acc. Batch 8 nodes -> LDS [8][72] rows,
// then round-8-verified MFMA phase (rows 8-15 garbage, es<2 write guard).
// ---------------------------------------------------------------------------
__global__ __launch_bounds__(256) void k_fuse2(
    const uint4* __restrict__ u1v8, const uint4* __restrict__ v1v8, // [NN*8]
    const int* __restrict__ src, const int* __restrict__ dst,
    const float* __restrict__ dists,
    const unsigned short* __restrict__ wcat2,  // [64][64] bf16
    const float* __restrict__ bu2, const float* __restrict__ bv2,
    unsigned short* __restrict__ u2b,          // [NN][32] bf16
    unsigned short* __restrict__ v2b)          // [NN][32] bf16
{
    __shared__ unsigned short s_x2[4][16 * 72];   // per-wave [16 rows][72] tile
    int tid = threadIdx.x;
    int wv = __builtin_amdgcn_readfirstlane(tid >> 6);
    int lane = tid & 63;
    int c = lane & 7;       // 16B chunk: dims c*8..c*8+7
    int es = lane >> 3;     // edge subgroup 0..7 (k = es*4 + kk)
    int c16 = lane & 15;    // MFMA: out-col & A-row
    int es4 = lane >> 4;    // MFMA: k-group & row-group
    // ---- one-time: preload B-fragments of W2cat and bias ----
    bfrag Bf[4][2];
#pragma unroll
    for (int t = 0; t < 4; ++t)
#pragma unroll
        for (int s = 0; s < 2; ++s) {
            uint4 raw = *reinterpret_cast<const uint4*>(
                wcat2 + (t * 16 + c16) * 64 + s * 32 + es4 * 8);
            Bf[t][s] = *reinterpret_cast<const bfrag*>(&raw);
        }
    float bb[4];
#pragma unroll
    for (int t = 0; t < 4; ++t)
        bb[t] = (t < 2) ? bu2[t * 16 + c16] : bv2[(t - 2) * 16 + c16];

    unsigned short* sx = &s_x2[wv][0];
    int slot = blockIdx.x * 4 + wv;
    int stride = gridDim.x * 4;
    const int nBatch = NN / 8;            // 6250
    for (int b = slot; b < nBatch; b += stride) {
        int n0 = b * 8;
        // ---- gather phase: 8 nodes, ushort8 table loads ----
        for (int i = 0; i < 8; ++i) {
            int base = (n0 + i) * KANCH + es * 4;
            int4   s4 = *reinterpret_cast<const int4*>(src + base);
            int4   d4 = *reinterpret_cast<const int4*>(dst + base);
            float4 p4 = *reinterpret_cast<const float4*>(dists + base);
            uint4 u0 = u1v8[(size_t)s4.x * 8 + c];
            uint4 u1 = u1v8[(size_t)s4.y * 8 + c];
            uint4 u2 = u1v8[(size_t)s4.z * 8 + c];
            uint4 u3 = u1v8[(size_t)s4.w * 8 + c];
            uint4 v0 = v1v8[(size_t)d4.x * 8 + c];
            uint4 v1 = v1v8[(size_t)d4.y * 8 + c];
            uint4 v2 = v1v8[(size_t)d4.z * 8 + c];
            uint4 v3 = v1v8[(size_t)d4.w * 8 + c];
            float a[8];
#pragma unroll
            for (int j = 0; j < 8; ++j) a[j] = 0.f;
#define ACC8(U, V, SP)                                                    \
            a[0] += fmaxf(fmaf(lo16((U).x), (SP), lo16((V).x)), 0.f);     \
            a[1] += fmaxf(fmaf(hi16((U).x), (SP), hi16((V).x)), 0.f);     \
            a[2] += fmaxf(fmaf(lo16((U).y), (SP), lo16((V).y)), 0.f);     \
            a[3] += fmaxf(fmaf(hi16((U).y), (SP), hi16((V).y)), 0.f);     \
            a[4] += fmaxf(fmaf(lo16((U).z), (SP), lo16((V).z)), 0.f);     \
            a[5] += fmaxf(fmaf(hi16((U).z), (SP), hi16((V).z)), 0.f);     \
            a[6] += fmaxf(fmaf(lo16((U).w), (SP), lo16((V).w)), 0.f);     \
            a[7] += fmaxf(fmaf(hi16((U).w), (SP), hi16((V).w)), 0.f);
            ACC8(u0, v0, p4.x)
            ACC8(u1, v1, p4.y)
            ACC8(u2, v2, p4.z)
            ACC8(u3, v3, p4.w)
#undef ACC8
            // reduce over the 8 edge subgroups (lane bits 3,4,5)
#pragma unroll
            for (int j = 0; j < 8; ++j) {
                a[j] += __shfl_xor(a[j], 8);
                a[j] += __shfl_xor(a[j], 16);
                a[j] += __shfl_xor(a[j], 32);
            }
            if (lane < 8) {        // es == 0 lanes hold the final 8 dims
                uint4 r;
                r.x = pack2(a[0] * 0.03125f, a[1] * 0.03125f);
                r.y = pack2(a[2] * 0.03125f, a[3] * 0.03125f);
                r.z = pack2(a[4] * 0.03125f, a[5] * 0.03125f);
                r.w = pack2(a[6] * 0.03125f, a[7] * 0.03125f);
                *reinterpret_cast<uint4*>(&sx[i * 72 + c * 8]) = r;
            }
        }
        // ---- MFMA phase (round-8 verified): rows 0..7 real ----
        bfrag A[2];
#pragma unroll
        for (int s = 0; s < 2; ++s)
            A[s] = *reinterpret_cast<const bfrag*>(
                &sx[c16 * 72 + s * 32 + es4 * 8]);
        ffrag acc[4];
#pragma unroll
        for (int t = 0; t < 4; ++t) {
            acc[t] = ffrag{0.f, 0.f, 0.f, 0.f};
#pragma unroll
            for (int s = 0; s < 2; ++s)
                acc[t] = __builtin_amdgcn_mfma_f32_16x16x32_bf16(
                    A[s], Bf[t][s], acc[t], 0, 0, 0);
        }
        if (es4 < 2) {                     // rows 0..7 are the real nodes
#pragma unroll
            for (int t = 0; t < 4; ++t) {
#pragma unroll
                for (int j = 0; j < 4; ++j) {
                    int node = n0 + es4 * 4 + j;
                    unsigned short o = f2bf(acc[t][j] + bb[t]);
                    if (t < 2) u2b[(size_t)node * 32 + t * 16 + c16] = o;
                    else       v2b[(size_t)node * 32 + (t - 2) * 16 + c16] = o;
                }
            }
        }
    }
}

// ---------------------------------------------------------------------------
// K3: layer-2 message + position dot + L2 normalize, ushort8 loads.
// lane = (es=lane>>2: edges k=es*2+kk, c=lane&3: chunk of 8 dims).
// 4 table loads/node (vs 8); A/B pair per iteration for MLP.
// c-reduce 2 shfls -> dot; es-reduce 4 shfls -> norm; indexed-shfl collect.
// ---------------------------------------------------------------------------
__global__ __launch_bounds__(256, 4) void k_out(
    const uint4* __restrict__ u2v8, const uint4* __restrict__ v2v8, // [NN*4]
    const int* __restrict__ src, const int* __restrict__ dst,
    const float* __restrict__ dists, const float* __restrict__ wp2,
    const float* __restrict__ bp2, float* __restrict__ out)
{
    int tid = threadIdx.x;
    int wv = __builtin_amdgcn_readfirstlane(tid >> 6);
    int lane = tid & 63;
    int c = lane & 3;       // dims c*8..c*8+7
    int es = lane >> 2;     // edge subgroup 0..15 (k = es*2 + kk)
    int slot = blockIdx.x * 4 + wv;
    int stride = gridDim.x * 4;
    float4 w8a = reinterpret_cast<const float4*>(wp2)[c * 2];
    float4 w8b = reinterpret_cast<const float4*>(wp2)[c * 2 + 1];
    float bp = bp2[0];
    const int nPairs = NN / 2;
    for (int p = slot; p < nPairs; p += stride) {
        int nA = p * 2, nB = nA + 1;
        int baseA = nA * KANCH + es * 2, baseB = nB * KANCH + es * 2;
        int2   sA = *reinterpret_cast<const int2*>(src + baseA);
        int2   dA = *reinterpret_cast<const int2*>(dst + baseA);
        float2 pA = *reinterpret_cast<const float2*>(dists + baseA);
        int2   sB = *reinterpret_cast<const int2*>(src + baseB);
        int2   dB = *reinterpret_cast<const int2*>(dst + baseB);
        float2 pB = *reinterpret_cast<const float2*>(dists + baseB);
        uint4 uA0 = u2v8[(size_t)sA.x * 4 + c];
        uint4 uA1 = u2v8[(size_t)sA.y * 4 + c];
        uint4 vA0 = v2v8[(size_t)dA.x * 4 + c];
        uint4 vA1 = v2v8[(size_t)dA.y * 4 + c];
        uint4 uB0 = u2v8[(size_t)sB.x * 4 + c];
        uint4 uB1 = u2v8[(size_t)sB.y * 4 + c];
        uint4 vB0 = v2v8[(size_t)dB.x * 4 + c];
        uint4 vB1 = v2v8[(size_t)dB.y * 4 + c];
#define DOT8(U, V, SP)                                                    \
        ( fmaxf(fmaf(lo16((U).x), (SP), lo16((V).x)), 0.f) * w8a.x        \
        + fmaxf(fmaf(hi16((U).x), (SP), hi16((V).x)), 0.f) * w8a.y        \
        + fmaxf(fmaf(lo16((U).y), (SP), lo16((V).y)), 0.f) * w8a.z        \
        + fmaxf(fmaf(hi16((U).y), (SP), hi16((V).y)), 0.f) * w8a.w        \
        + fmaxf(fmaf(lo16((U).z), (SP), lo16((V).z)), 0.f) * w8b.x        \
        + fmaxf(fmaf(hi16((U).z), (SP), hi16((V).z)), 0.f) * w8b.y        \
        + fmaxf(fmaf(lo16((U).w), (SP), lo16((V).w)), 0.f) * w8b.z        \
        + fmaxf(fmaf(hi16((U).w), (SP), hi16((V).w)), 0.f) * w8b.w )
        float qA0 = DOT8(uA0, vA0, pA.x);
        float qA1 = DOT8(uA1, vA1, pA.y);
        float qB0 = DOT8(uB0, vB0, pB.x);
        float qB1 = DOT8(uB1, vB1, pB.y);
#undef DOT8
        // reduce over the 4 chunk lanes (bits 0,1)
        qA0 += __shfl_xor(qA0, 1); qA0 += __shfl_xor(qA0, 2);
        qA1 += __shfl_xor(qA1, 1); qA1 += __shfl_xor(qA1, 2);
        qB0 += __shfl_xor(qB0, 1); qB0 += __shfl_xor(qB0, 2);
        qB1 += __shfl_xor(qB1, 1); qB1 += __shfl_xor(qB1, 2);
        qA0 += bp; qA1 += bp; qB0 += bp; qB1 += bp;
        // norm: sum q^2 over the 16 edge subgroups (lane bits 2..5)
        float ssA = qA0 * qA0 + qA1 * qA1;
        float ssB = qB0 * qB0 + qB1 * qB1;
        ssA += __shfl_xor(ssA, 4);  ssA += __shfl_xor(ssA, 8);
        ssA += __shfl_xor(ssA, 16); ssA += __shfl_xor(ssA, 32);
        ssB += __shfl_xor(ssB, 4);  ssB += __shfl_xor(ssB, 8);
        ssB += __shfl_xor(ssB, 16); ssB += __shfl_xor(ssB, 32);
        // component t: edge k=t, es=t>>1, kk=t&1; q lives at lanes (t>>1)*4
        int t = lane & 31;
        int srcl = (t >> 1) * 4;
        float a0 = __shfl(qA0, srcl), a1 = __shfl(qA1, srcl);
        float b0 = __shfl(qB0, srcl), b1 = __shfl(qB1, srcl);
        float qa = (t & 1) ? a1 : a0;
        float qb = (t & 1) ? b1 : b0;
        float q  = (lane < 32) ? qa : qb;
        float ss = (lane < 32) ? ssA : ssB;
        float den = fmaxf(sqrtf(ss), 1e-12f);
        float o = q / den;
        if (lane < 32) out[(size_t)nA * KANCH + t] = o;
        else           out[(size_t)nB * KANCH + t] = o;
    }
}

// ---------------------------------------------------------------------------
extern "C" void kernel_launch(void* const* d_in, const int* in_sizes, int n_in,
                              void* d_out, int out_size, void* d_ws, size_t ws_size,
                              hipStream_t stream)
{
    const float* feat  = (const float*)d_in[0];
    const float* dists = (const float*)d_in[1];
    const int*   src   = (const int*)d_in[2];
    const int*   dst   = (const int*)d_in[3];
    const float* w_pre = (const float*)d_in[4];
    const float* b_pre = (const float*)d_in[5];
    const float* Wu1   = (const float*)d_in[6];
    const float* bu1   = (const float*)d_in[7];
    const float* Wv1   = (const float*)d_in[8];
    const float* bv1   = (const float*)d_in[9];
    // d_in[10]=wp1, d_in[11]=bp1: layer-1 position output is discarded
    const float* Wu2   = (const float*)d_in[12];
    const float* bu2   = (const float*)d_in[13];
    const float* Wv2   = (const float*)d_in[14];
    const float* bv2   = (const float*)d_in[15];
    const float* wp2   = (const float*)d_in[16];
    const float* bp2   = (const float*)d_in[17];
    float* out = (float*)d_out;

    // workspace (~19.2 MB)
    unsigned short* wcat1 = (unsigned short*)d_ws;           // 16384 us
    float* bias1 = (float*)(wcat1 + 16384);                  // 128 f
    unsigned short* wcat2 = (unsigned short*)(bias1 + 128);  // 4096 us
    unsigned short* u1b = wcat2 + 4096;                      // [NN][64]
    unsigned short* v1b = u1b + (size_t)NN * 64;             // [NN][64]
    unsigned short* u2b = v1b + (size_t)NN * 64;             // [NN][32]
    unsigned short* v2b = u2b + (size_t)NN * 32;             // [NN][32]

    k_prep<<<81, 256, 0, stream>>>(w_pre, b_pre, Wu1, bu1, Wv1, bv1,
                                   Wu2, Wv2, wcat1, bias1, wcat2);
    k_gemm1<<<782, 256, 0, stream>>>(feat, wcat1, bias1, u1b, v1b, NN / 16);
    k_fuse2<<<1563, 256, 0, stream>>>((const uint4*)u1b, (const uint4*)v1b,
                                      src, dst, dists, wcat2, bu2, bv2,
                                      u2b, v2b);
    k_out<<<2048, 256, 0, stream>>>((const uint4*)u2b, (const uint4*)v2b,
                                    src, dst, dists, wp2, bp2, out);
}